// Round 7
// baseline (1296.109 us; speedup 1.0000x reference)
//
#include <hip/hip_runtime.h>

// DGP-RF embeddings, fused MFMA. Round 15: A-fragments in REGISTERS.
// R14 lesson (falsifier fired): VALU -10pts, wall time flat => VALU was never
// critical. Per-CU LDS arithmetic: GEMM1 A-frag re-reads = 1024 LDS reads/wave
// (~290us/CU) -- the LDS pipe (~55-60% busy) is the real dominant term.
// KEY FACT all prior rounds missed: A-frags are chunk-INDEPENDENT. Re-split
// GEMM1 ownership (wave owns 16 points x all 64 RFs, not 16 RFs x 64 points):
//   - each wave loads its 16 points x 256 dims of X ONCE from global into
//     48 VGPRs (axr bf16, aqr fp8 x^2); Xb/Xq8 LDS tables DELETED.
//   - W1 now read by all waves (4x redundancy) via L1/L2 (768KB, L2-resident)
//     instead of the saturated LDS pipe.
//   - MFMA count, moments LUT, GEMM2, barriers, epilogue: unchanged.
// LDS drops 73.7KB -> ~23KB (T tables + LUT + sidx). Regs ~230 @ 2blk/CU.
// Predicted: LDS 24K, conflicts 1.5-2.5e7, VGPR ~230, Mfma ~27, VALU ~33,
// fused ~390-450us. Falsifier: >=510us => barrier/latency floor, stop.

#define NPTS   131072
#define SGRP   16384
#define DIN    256
#define NRF    1024
#define DOUT   128
#define MT     64            // points per WG
#define NWG    (NPTS / MT)   // 2048

#define TMLD   72    // bf16 m' row stride (144B, 16B-aligned)
#define TVLD   72    // fp8 v'/m'^2 row stride

typedef unsigned short ushort_t;
typedef unsigned char  uchar_t;
typedef __attribute__((ext_vector_type(8))) short bf16x8;
typedef __attribute__((ext_vector_type(4))) float f32x4;
typedef __attribute__((ext_vector_type(4))) float f32x4v;

__device__ __forceinline__ unsigned short f2bf(float f) {
  unsigned u = __float_as_uint(f);
  u += 0x7fffu + ((u >> 16) & 1u);   // round-to-nearest-even
  return (unsigned short)(u >> 16);
}

// pack 2 floats -> 2 fp8 e4m3 bytes into (HI? bytes 2,3 : bytes 0,1) of old
template <bool HI>
__device__ __forceinline__ unsigned cvt2_fp8(float a, float b, unsigned old) {
#if __has_builtin(__builtin_amdgcn_cvt_pk_fp8_f32)
  return __builtin_amdgcn_cvt_pk_fp8_f32(a, b, old, HI);
#else
  auto enc = [](float x) -> unsigned {
    if (!(x > 0.00097656f)) return 0u;
    if (x >= 448.f) return 0x7Eu;
    union { float f; unsigned u; } v; v.f = x;
    int e = (int)(v.u >> 23) - 127;
    if (e < -6) { int n = (int)(x * 512.f + 0.5f); return (unsigned)n; }
    v.u += 0x0007FFFFu + ((v.u >> 20) & 1u);
    e = (int)(v.u >> 23) - 127;
    if (e > 8) return 0x7Eu;
    return (unsigned)(((e + 7) << 3) | ((v.u >> 20) & 7u));
  };
  unsigned p = (enc(a) | (enc(b) << 8));
  return HI ? ((old & 0x0000ffffu) | (p << 16)) : ((old & 0xffff0000u) | p);
#endif
}

__device__ __forceinline__ float fast_rcp(float x) {
#if __has_builtin(__builtin_amdgcn_rcpf)
  return __builtin_amdgcn_rcpf(x);
#else
  return 1.0f / x;
#endif
}
__device__ __forceinline__ float fast_rsq(float x) {
#if __has_builtin(__builtin_amdgcn_rsqf)
  return __builtin_amdgcn_rsqf(x);
#else
  return rsqrtf(x);
#endif
}

// ---------------- kernel 0: detect whether X_idx is int32 or int64 -------------
__global__ void detect_idx_kernel(const unsigned* __restrict__ raw,
                                  int* __restrict__ flag) {
  __shared__ int any_nz;
  if (threadIdx.x == 0) any_nz = 0;
  __syncthreads();
  if (raw[2 * threadIdx.x + 1] != 0u) atomicOr(&any_nz, 1);
  __syncthreads();
  if (threadIdx.x == 0) *flag = (any_nz == 0) ? 1 : 0;   // 1 => int64
}

// ---------------- kernel 0b: build 256-entry lerp table for h(z), w(z) --------
// entry i covers z in [i/16-8, i/16-8+1/16); stores {h0, h1-h0, w0, w1-w0}.
__global__ void moments_table_kernel(float4* __restrict__ tab) {
  int i = threadIdx.x;   // 0..255
  float z0 = (float)i * 0.0625f - 8.0f;
  float h[2], w[2];
#pragma unroll
  for (int j = 0; j < 2; ++j) {
    float z = z0 + 0.0625f * j;
    float Phi = 0.5f * (1.0f + erff(z * 0.70710678118654752f));
    float phi = 0.3989422804014327f * expf(-0.5f * z * z);
    float hh = z * Phi + phi;
    float gg = (z * z + 1.0f) * Phi + z * phi;
    h[j] = hh;
    w[j] = gg - hh * hh;
  }
  tab[i] = make_float4(h[0], h[1] - h[0], w[0], w[1] - w[0]);
}

// ---------------- kernel 1: convert weights (bf16 mean path, fp8 var path) ----
__global__ __launch_bounds__(256) void convert_kernel(
    const float* __restrict__ W1mu, const float* __restrict__ W1var,
    const float* __restrict__ W2mu, const float* __restrict__ W2var,
    ushort_t* __restrict__ w1mu_bf, uchar_t* __restrict__ w1var8,
    ushort_t* __restrict__ w2mu_bf, uchar_t* __restrict__ w2b8,
    uchar_t* __restrict__ w2var8) {
  int i4 = (blockIdx.x * 256 + threadIdx.x) * 4;   // grid covers 262144
  {
    f32x4v m = *(const f32x4v*)(W1mu + i4);
    ushort4 b; b.x = f2bf(m[0]); b.y = f2bf(m[1]); b.z = f2bf(m[2]); b.w = f2bf(m[3]);
    *(ushort4*)(w1mu_bf + i4) = b;
    f32x4v v = *(const f32x4v*)(W1var + i4);
    unsigned p = cvt2_fp8<false>(v[0] * 256.f, v[1] * 256.f, 0u);
    p = cvt2_fp8<true>(v[2] * 256.f, v[3] * 256.f, p);
    *(unsigned*)(w1var8 + i4) = p;
  }
  if (i4 < NRF * DOUT) {
    f32x4v m = *(const f32x4v*)(W2mu + i4);
    f32x4v v = *(const f32x4v*)(W2var + i4);
    ushort4 b; b.x = f2bf(m[0]); b.y = f2bf(m[1]); b.z = f2bf(m[2]); b.w = f2bf(m[3]);
    *(ushort4*)(w2mu_bf + i4) = b;
    unsigned pb = cvt2_fp8<false>(fmaf(m[0], m[0], v[0]) * 256.f,
                                  fmaf(m[1], m[1], v[1]) * 256.f, 0u);
    pb = cvt2_fp8<true>(fmaf(m[2], m[2], v[2]) * 256.f,
                        fmaf(m[3], m[3], v[3]) * 256.f, pb);
    *(unsigned*)(w2b8 + i4) = pb;
    unsigned pv = cvt2_fp8<false>(v[0] * 256.f, v[1] * 256.f, 0u);
    pv = cvt2_fp8<true>(v[2] * 256.f, v[3] * 256.f, pv);
    *(unsigned*)(w2var8 + i4) = pv;
  }
}

// ---------------- kernel 2: fused DGP-RF block --------------------------------
__global__ __launch_bounds__(256, 2) void fused_kernel(
    const float* __restrict__ X,
    const unsigned* __restrict__ Xidx_raw,
    const ushort_t* __restrict__ W1mu, const uchar_t* __restrict__ W1var8,
    const ushort_t* __restrict__ W2mu, const uchar_t* __restrict__ W2b8,
    const uchar_t* __restrict__ W2var8,
    const float4* __restrict__ htab_g,
    const int* __restrict__ flag64,
    float* __restrict__ acc_means, float* __restrict__ acc_vars) {
  __shared__ ushort_t Tm[MT * TMLD];   //  9.2 KB bf16 m'    [point][rf]
  __shared__ uchar_t  Tv8[MT * TVLD];  //  4.6 KB fp8 v'
  __shared__ uchar_t  T38[MT * TVLD];  //  4.6 KB fp8 m'^2
  __shared__ float4   htab[256];       //  4.0 KB moments lerp table
  __shared__ int sidx[MT];             //  total ~22.8 KB

  const int tid = threadIdx.x;
  const int p0  = blockIdx.x * MT;
  const int is64 = *flag64;

  if (tid < MT) {
    int p = p0 + tid;
    sidx[tid] = (int)(is64 ? Xidx_raw[2 * (size_t)p] : Xidx_raw[p]);
  }
  htab[tid] = htab_g[tid];   // 256 threads, 256 entries

  const int lane = tid & 63;
  const int wave = tid >> 6;
  const int l16  = lane & 15;
  const int quad = lane >> 4;
  const int qoff = quad * 8;

  // ---- A-fragments: this wave's 16 points x 256 dims, in registers, ONCE ----
  // axr[k] = bf16 x at cols k*32+qoff..+8 of row (wave*16+l16)
  // aqr[k] = fp8  x^2, same slice
  bf16x8 axr[8]; long long aqr[8];
  {
    const float* xrow = X + (size_t)(p0 + wave * 16 + l16) * DIN;
#pragma unroll
    for (int k = 0; k < 8; ++k) {
      f32x4v xa = *(const f32x4v*)(xrow + k * 32 + qoff);
      f32x4v xb = *(const f32x4v*)(xrow + k * 32 + qoff + 4);
      bf16x8 a;
      a[0] = (short)f2bf(xa[0]); a[1] = (short)f2bf(xa[1]);
      a[2] = (short)f2bf(xa[2]); a[3] = (short)f2bf(xa[3]);
      a[4] = (short)f2bf(xb[0]); a[5] = (short)f2bf(xb[1]);
      a[6] = (short)f2bf(xb[2]); a[7] = (short)f2bf(xb[3]);
      axr[k] = a;
      unsigned lo = cvt2_fp8<false>(xa[0] * xa[0], xa[1] * xa[1], 0u);
      lo = cvt2_fp8<true>(xa[2] * xa[2], xa[3] * xa[3], lo);
      unsigned hi = cvt2_fp8<false>(xb[0] * xb[0], xb[1] * xb[1], 0u);
      hi = cvt2_fp8<true>(xb[2] * xb[2], xb[3] * xb[3], hi);
      aqr[k] = (long long)(((unsigned long long)hi << 32) | (unsigned long long)lo);
    }
  }
  __syncthreads();   // htab/sidx visible (also spaces the global burst)

  const int nrow0 = (wave * 2 + 0) * 16 + l16;   // GEMM2 B rows (dout)
  const int nrow1 = (wave * 2 + 1) * 16 + l16;

  f32x4 acc_mo[4][2], acc_vo[4][2];
#pragma unroll
  for (int mt = 0; mt < 4; ++mt)
#pragma unroll
    for (int j = 0; j < 2; ++j) {
      acc_mo[mt][j] = (f32x4){0.f, 0.f, 0.f, 0.f};
      acc_vo[mt][j] = (f32x4){0.f, 0.f, 0.f, 0.f};
    }

#pragma unroll 1
  for (int c = 0; c < 16; ++c) {   // 16 chunks x 64 RFs
    // ---- GEMM1: A = X frags (regs), B = W1 rows c*64 + j*16 + l16 (global) ----
    const ushort_t* w1mB = W1mu   + (size_t)(c * 64 + l16) * DIN + qoff;
    const uchar_t*  w1vB = W1var8 + (size_t)(c * 64 + l16) * DIN + qoff;
    f32x4 am[4], av[4];
#pragma unroll
    for (int j = 0; j < 4; ++j) {
      am[j] = (f32x4){0.f, 0.f, 0.f, 0.f};
      av[j] = (f32x4){0.f, 0.f, 0.f, 0.f};
    }
#pragma unroll
    for (int k = 0; k < 8; ++k) {
#pragma unroll
      for (int j = 0; j < 4; ++j) {
        bf16x8 bmu = *(const bf16x8*)(w1mB + (size_t)(j * 16) * DIN + k * 32);
        long long bvr = *(const long long*)(w1vB + (size_t)(j * 16) * DIN + k * 32);
        am[j] = __builtin_amdgcn_mfma_f32_16x16x32_bf16(axr[k], bmu, am[j], 0, 0, 0);
        av[j] = __builtin_amdgcn_mfma_f32_16x16x32_fp8_fp8(aqr[k], bvr, av[j], 0, 0, 0);
      }
    }

    // ---- preload GEMM2 B (global; latency overlaps moments) ----
    const ushort_t* w2m0 = W2mu + (size_t)nrow0 * NRF + c * 64 + qoff;
    const ushort_t* w2m1 = W2mu + (size_t)nrow1 * NRF + c * 64 + qoff;
    const uchar_t* w2b0 = W2b8 + (size_t)nrow0 * NRF + c * 64 + qoff;
    const uchar_t* w2b1 = W2b8 + (size_t)nrow1 * NRF + c * 64 + qoff;
    const uchar_t* w2v0 = W2var8 + (size_t)nrow0 * NRF + c * 64 + qoff;
    const uchar_t* w2v1 = W2var8 + (size_t)nrow1 * NRF + c * 64 + qoff;
    bf16x8 b2m[2][2]; long long b2b[2][2], b2v[2][2];
#pragma unroll
    for (int k2 = 0; k2 < 2; ++k2) {
      b2m[0][k2] = *(const bf16x8*)(w2m0 + k2 * 32);
      b2m[1][k2] = *(const bf16x8*)(w2m1 + k2 * 32);
      b2b[0][k2] = *(const long long*)(w2b0 + k2 * 32);
      b2b[1][k2] = *(const long long*)(w2b1 + k2 * 32);
      b2v[0][k2] = *(const long long*)(w2v0 + k2 * 32);
      b2v[1][k2] = *(const long long*)(w2v1 + k2 * 32);
    }

    // Barrier A: prior chunk's GEMM2 T-reads complete before overwrite.
    __syncthreads();

    // ---- ReLU moments via LUT -> T[pt][rf_local] ----
    // value (j, r): pt = wave*16 + quad*4 + r, rf_local = j*16 + l16
#pragma unroll
    for (int j = 0; j < 4; ++j) {
#pragma unroll
      for (int r = 0; r < 4; ++r) {
        float mu  = am[j][r];
        float vpe = fmaf(av[j][r], 0.00390625f, 1e-8f);  // descale + eps
        float rsq = fast_rsq(vpe);
        float z   = mu * rsq;
        float s   = vpe * rsq;
        float zc  = fminf(fmaxf(z, -8.0f), 7.96875f);
        float u   = fmaf(zc, 16.0f, 128.0f);              // [0, 255.5]
        float fu  = floorf(u);
        float f   = u - fu;
        float4 hv = htab[(int)fu];
        float h   = fmaf(f, hv.y, hv.x);
        float w   = fmaf(f, hv.w, hv.z);
        float mo  = (z > 7.9f) ? mu : s * h;              // exact linear tail
        float vo  = fmaxf(vpe * w, 1e-6f);
        int row = wave * 16 + quad * 4 + r;
        int col = j * 16 + l16;
        Tm[row * TMLD + col] = f2bf(mo);
        Tv8[row * TVLD + col] = (uchar_t)(cvt2_fp8<false>(vo, vo, 0u) & 0xffu);
        T38[row * TVLD + col] = (uchar_t)(cvt2_fp8<false>(mo * mo, mo * mo, 0u) & 0xffu);
      }
    }
    // Barrier B: T writes visible.
    __syncthreads();

    // ---- GEMM2 over this 64-RF chunk (2 K-steps) ----
#pragma unroll
    for (int k2 = 0; k2 < 2; ++k2) {
#pragma unroll
      for (int mt = 0; mt < 4; ++mt) {
        int ar = mt * 16 + l16;
        bf16x8 fam = *(const bf16x8*)(Tm + ar * TMLD + k2 * 32 + qoff);
        long long fav = *(const long long*)(Tv8 + ar * TVLD + k2 * 32 + qoff);
        long long f3  = *(const long long*)(T38 + ar * TVLD + k2 * 32 + qoff);
        acc_mo[mt][0] = __builtin_amdgcn_mfma_f32_16x16x32_bf16(fam, b2m[0][k2], acc_mo[mt][0], 0, 0, 0);
        acc_mo[mt][1] = __builtin_amdgcn_mfma_f32_16x16x32_bf16(fam, b2m[1][k2], acc_mo[mt][1], 0, 0, 0);
        acc_vo[mt][0] = __builtin_amdgcn_mfma_f32_16x16x32_fp8_fp8(fav, b2b[0][k2], acc_vo[mt][0], 0, 0, 0);
        acc_vo[mt][1] = __builtin_amdgcn_mfma_f32_16x16x32_fp8_fp8(fav, b2b[1][k2], acc_vo[mt][1], 0, 0, 0);
        acc_vo[mt][0] = __builtin_amdgcn_mfma_f32_16x16x32_fp8_fp8(f3, b2v[0][k2], acc_vo[mt][0], 0, 0, 0);
        acc_vo[mt][1] = __builtin_amdgcn_mfma_f32_16x16x32_fp8_fp8(f3, b2v[1][k2], acc_vo[mt][1], 0, 0, 0);
      }
    }
  }

  // ---- epilogue: precision-weighted scatter (acc_vo carries x256 scale) ----
#pragma unroll
  for (int mt = 0; mt < 4; ++mt)
#pragma unroll
    for (int j = 0; j < 2; ++j) {
      int dim = (wave * 2 + j) * 16 + l16;
#pragma unroll
      for (int r = 0; r < 4; ++r) {
        int prow = mt * 16 + quad * 4 + r;
        float mo = acc_mo[mt][j][r];
        float vo = fmaf(acc_vo[mt][j][r], 0.00390625f, 1e-6f);
        float prec = fast_rcp(vo);
        size_t o = (size_t)sidx[prow] * DOUT + dim;
        unsafeAtomicAdd(acc_means + o, prec * mo);
        unsafeAtomicAdd(acc_vars + o, prec);
      }
    }
}

// ---------------- kernel 3: finalize ------------------------------------------
__global__ __launch_bounds__(256) void finalize_kernel(float* __restrict__ means,
                                                       float* __restrict__ vars) {
  int i = blockIdx.x * 256 + threadIdx.x;   // covers S*DOUT exactly
  float p  = vars[i];
  float pm = means[i];
  float var = 1.0f / p;
  means[i] = pm * var;
  vars[i]  = var;
}

extern "C" void kernel_launch(void* const* d_in, const int* in_sizes, int n_in,
                              void* d_out, int out_size, void* d_ws, size_t ws_size,
                              hipStream_t stream) {
  const float*    X     = (const float*)d_in[0];
  const unsigned* Xidx  = (const unsigned*)d_in[1];
  const float*    W1mu  = (const float*)d_in[2];
  const float*    W1var = (const float*)d_in[3];
  const float*    W2mu  = (const float*)d_in[4];
  const float*    W2var = (const float*)d_in[5];
  float* out = (float*)d_out;

  ushort_t* w1mu_bf = (ushort_t*)d_ws;                    // 524288 B
  uchar_t*  w1var8  = (uchar_t*)(w1mu_bf + NRF * DIN);    // 262144 B
  ushort_t* w2mu_bf = (ushort_t*)(w1var8 + NRF * DIN);    // 262144 B
  uchar_t*  w2b8    = (uchar_t*)(w2mu_bf + NRF * DOUT);   // 131072 B
  uchar_t*  w2var8  = w2b8 + NRF * DOUT;                  // 131072 B
  float4*   htab    = (float4*)(w2var8 + NRF * DOUT);     // 4096 B (16-aligned)
  int* flag = (int*)(htab + 256);

  (void)hipMemsetAsync(d_out, 0, (size_t)out_size * sizeof(float), stream);
  detect_idx_kernel<<<1, 256, 0, stream>>>(Xidx, flag);
  moments_table_kernel<<<1, 256, 0, stream>>>(htab);
  convert_kernel<<<(NRF * DIN) / 4 / 256, 256, 0, stream>>>(
      W1mu, W1var, W2mu, W2var, w1mu_bf, w1var8, w2mu_bf, w2b8, w2var8);
  fused_kernel<<<NWG, 256, 0, stream>>>(
      X, Xidx, w1mu_bf, w1var8, w2mu_bf, w2b8, w2var8, htab, flag,
      out, out + (size_t)SGRP * DOUT);
  finalize_kernel<<<(SGRP * DOUT) / 256, 256, 0, stream>>>(
      out, out + (size_t)SGRP * DOUT);
}

// Round 8
// 1037.018 us; speedup vs baseline: 1.2498x; 1.2498x over previous
//
#include <hip/hip_runtime.h>

// DGP-RF embeddings, fused MFMA. Round 16: MT=32, X A-frags resident in regs.
// R15 post-mortem: right target (GEMM1 A-LDS reads ~ half of the ~280us/CU
// LDS-pipe serialization), wrong mechanism (W1 moved to in-loop global loads,
// sank, latency-serialized; 3rd repeat of the R10/R12 failure mode).
// Invariance: whichever GEMM1 operand is in LDS costs the same reads. Only
// fix: hold the chunk-INVARIANT operand (X) in VGPRs for the whole kernel.
// MT=32 makes the A-set fit: axr 64 + aqr 32 = 96 regs; total ~230-250 < 256.
// W1/W2 keep the PROVEN R8 pattern (hoisted global frags, 16+12/chunk).
// Xb/Xq8 LDS deleted -> GEMM1 does ZERO LDS ops; LDS/chunk-wave 152 -> 44.
// Costs: 4096 blocks (2x barriers, ~+30us), X re-read 4x via L1/L2.
// Predicted: LDS ~14KB, VGPR 210-250, conflicts ~1.4e7, Mfma ~26, VALU ~34,
// fused ~400-440us. Falsifier: >=510us clean => global-latency/barrier floor.

#define NPTS   131072
#define SGRP   16384
#define DIN    256
#define NRF    1024
#define DOUT   128
#define MT     32            // points per WG (A-frags must fit in regs)
#define NMT    (MT / 16)     // 2
#define NWG    (NPTS / MT)   // 4096

#define TMLD   72    // bf16 m' row stride (144B, 16B-aligned)
#define TVLD   72    // fp8 v'/m'^2 row stride

typedef unsigned short ushort_t;
typedef unsigned char  uchar_t;
typedef __attribute__((ext_vector_type(8))) short bf16x8;
typedef __attribute__((ext_vector_type(4))) float f32x4;
typedef __attribute__((ext_vector_type(4))) float f32x4v;

__device__ __forceinline__ unsigned short f2bf(float f) {
  unsigned u = __float_as_uint(f);
  u += 0x7fffu + ((u >> 16) & 1u);   // round-to-nearest-even
  return (unsigned short)(u >> 16);
}

// pack 2 floats -> 2 fp8 e4m3 bytes into (HI? bytes 2,3 : bytes 0,1) of old
template <bool HI>
__device__ __forceinline__ unsigned cvt2_fp8(float a, float b, unsigned old) {
#if __has_builtin(__builtin_amdgcn_cvt_pk_fp8_f32)
  return __builtin_amdgcn_cvt_pk_fp8_f32(a, b, old, HI);
#else
  auto enc = [](float x) -> unsigned {
    if (!(x > 0.00097656f)) return 0u;
    if (x >= 448.f) return 0x7Eu;
    union { float f; unsigned u; } v; v.f = x;
    int e = (int)(v.u >> 23) - 127;
    if (e < -6) { int n = (int)(x * 512.f + 0.5f); return (unsigned)n; }
    v.u += 0x0007FFFFu + ((v.u >> 20) & 1u);
    e = (int)(v.u >> 23) - 127;
    if (e > 8) return 0x7Eu;
    return (unsigned)(((e + 7) << 3) | ((v.u >> 20) & 7u));
  };
  unsigned p = (enc(a) | (enc(b) << 8));
  return HI ? ((old & 0x0000ffffu) | (p << 16)) : ((old & 0xffff0000u) | p);
#endif
}

__device__ __forceinline__ float fast_rcp(float x) {
#if __has_builtin(__builtin_amdgcn_rcpf)
  return __builtin_amdgcn_rcpf(x);
#else
  return 1.0f / x;
#endif
}
__device__ __forceinline__ float fast_rsq(float x) {
#if __has_builtin(__builtin_amdgcn_rsqf)
  return __builtin_amdgcn_rsqf(x);
#else
  return rsqrtf(x);
#endif
}

// ---------------- kernel 0: detect whether X_idx is int32 or int64 -------------
__global__ void detect_idx_kernel(const unsigned* __restrict__ raw,
                                  int* __restrict__ flag) {
  __shared__ int any_nz;
  if (threadIdx.x == 0) any_nz = 0;
  __syncthreads();
  if (raw[2 * threadIdx.x + 1] != 0u) atomicOr(&any_nz, 1);
  __syncthreads();
  if (threadIdx.x == 0) *flag = (any_nz == 0) ? 1 : 0;   // 1 => int64
}

// ---------------- kernel 0b: build 256-entry lerp table for h(z), w(z) --------
// entry i covers z in [i/16-8, i/16-8+1/16); stores {h0, h1-h0, w0, w1-w0}.
__global__ void moments_table_kernel(float4* __restrict__ tab) {
  int i = threadIdx.x;   // 0..255
  float z0 = (float)i * 0.0625f - 8.0f;
  float h[2], w[2];
#pragma unroll
  for (int j = 0; j < 2; ++j) {
    float z = z0 + 0.0625f * j;
    float Phi = 0.5f * (1.0f + erff(z * 0.70710678118654752f));
    float phi = 0.3989422804014327f * expf(-0.5f * z * z);
    float hh = z * Phi + phi;
    float gg = (z * z + 1.0f) * Phi + z * phi;
    h[j] = hh;
    w[j] = gg - hh * hh;
  }
  tab[i] = make_float4(h[0], h[1] - h[0], w[0], w[1] - w[0]);
}

// ---------------- kernel 1: convert weights (bf16 mean path, fp8 var path) ----
__global__ __launch_bounds__(256) void convert_kernel(
    const float* __restrict__ W1mu, const float* __restrict__ W1var,
    const float* __restrict__ W2mu, const float* __restrict__ W2var,
    ushort_t* __restrict__ w1mu_bf, uchar_t* __restrict__ w1var8,
    ushort_t* __restrict__ w2mu_bf, uchar_t* __restrict__ w2b8,
    uchar_t* __restrict__ w2var8) {
  int i4 = (blockIdx.x * 256 + threadIdx.x) * 4;   // grid covers 262144
  {
    f32x4v m = *(const f32x4v*)(W1mu + i4);
    ushort4 b; b.x = f2bf(m[0]); b.y = f2bf(m[1]); b.z = f2bf(m[2]); b.w = f2bf(m[3]);
    *(ushort4*)(w1mu_bf + i4) = b;
    f32x4v v = *(const f32x4v*)(W1var + i4);
    unsigned p = cvt2_fp8<false>(v[0] * 256.f, v[1] * 256.f, 0u);
    p = cvt2_fp8<true>(v[2] * 256.f, v[3] * 256.f, p);
    *(unsigned*)(w1var8 + i4) = p;
  }
  if (i4 < NRF * DOUT) {
    f32x4v m = *(const f32x4v*)(W2mu + i4);
    f32x4v v = *(const f32x4v*)(W2var + i4);
    ushort4 b; b.x = f2bf(m[0]); b.y = f2bf(m[1]); b.z = f2bf(m[2]); b.w = f2bf(m[3]);
    *(ushort4*)(w2mu_bf + i4) = b;
    unsigned pb = cvt2_fp8<false>(fmaf(m[0], m[0], v[0]) * 256.f,
                                  fmaf(m[1], m[1], v[1]) * 256.f, 0u);
    pb = cvt2_fp8<true>(fmaf(m[2], m[2], v[2]) * 256.f,
                        fmaf(m[3], m[3], v[3]) * 256.f, pb);
    *(unsigned*)(w2b8 + i4) = pb;
    unsigned pv = cvt2_fp8<false>(v[0] * 256.f, v[1] * 256.f, 0u);
    pv = cvt2_fp8<true>(v[2] * 256.f, v[3] * 256.f, pv);
    *(unsigned*)(w2var8 + i4) = pv;
  }
}

// ---------------- kernel 2: fused DGP-RF block --------------------------------
__global__ __launch_bounds__(256, 2) void fused_kernel(
    const float* __restrict__ X,
    const unsigned* __restrict__ Xidx_raw,
    const ushort_t* __restrict__ W1mu, const uchar_t* __restrict__ W1var8,
    const ushort_t* __restrict__ W2mu, const uchar_t* __restrict__ W2b8,
    const uchar_t* __restrict__ W2var8,
    const float4* __restrict__ htab_g,
    const int* __restrict__ flag64,
    float* __restrict__ acc_means, float* __restrict__ acc_vars) {
  __shared__ ushort_t Tm[MT * TMLD];   //  4.6 KB bf16 m'    [point][rf]
  __shared__ uchar_t  Tv8[MT * TVLD];  //  2.3 KB fp8 v'
  __shared__ uchar_t  T38[MT * TVLD];  //  2.3 KB fp8 m'^2
  __shared__ float4   htab[256];       //  4.0 KB moments lerp table
  __shared__ int sidx[MT];             //  total ~13.3 KB

  const int tid = threadIdx.x;
  const int p0  = blockIdx.x * MT;
  const int is64 = *flag64;

  if (tid < MT) {
    int p = p0 + tid;
    sidx[tid] = (int)(is64 ? Xidx_raw[2 * (size_t)p] : Xidx_raw[p]);
  }
  htab[tid] = htab_g[tid];   // 256 threads, 256 entries

  const int lane = tid & 63;
  const int wave = tid >> 6;
  const int l16  = lane & 15;
  const int quad = lane >> 4;
  const int qoff = quad * 8;

  // ---- A-fragments: rows mt*16+l16 (mt=0,1), cols k*32+qoff..+8, in regs ----
  // Loaded from global X ONCE; converted to bf16 (axr) and fp8 x^2 (aqr).
  // GEMM1 then performs ZERO LDS reads.
  bf16x8 axr[NMT][8]; long long aqr[NMT][8];
#pragma unroll
  for (int mt = 0; mt < NMT; ++mt) {
    const float* xrow = X + (size_t)(p0 + mt * 16 + l16) * DIN;
#pragma unroll
    for (int k = 0; k < 8; ++k) {
      f32x4v xa = *(const f32x4v*)(xrow + k * 32 + qoff);
      f32x4v xb = *(const f32x4v*)(xrow + k * 32 + qoff + 4);
      bf16x8 a;
      a[0] = (short)f2bf(xa[0]); a[1] = (short)f2bf(xa[1]);
      a[2] = (short)f2bf(xa[2]); a[3] = (short)f2bf(xa[3]);
      a[4] = (short)f2bf(xb[0]); a[5] = (short)f2bf(xb[1]);
      a[6] = (short)f2bf(xb[2]); a[7] = (short)f2bf(xb[3]);
      axr[mt][k] = a;
      unsigned lo = cvt2_fp8<false>(xa[0] * xa[0], xa[1] * xa[1], 0u);
      lo = cvt2_fp8<true>(xa[2] * xa[2], xa[3] * xa[3], lo);
      unsigned hi = cvt2_fp8<false>(xb[0] * xb[0], xb[1] * xb[1], 0u);
      hi = cvt2_fp8<true>(xb[2] * xb[2], xb[3] * xb[3], hi);
      aqr[mt][k] = (long long)(((unsigned long long)hi << 32) | (unsigned long long)lo);
    }
  }
  __syncthreads();   // htab/sidx visible

  const int nrow0 = (wave * 2 + 0) * 16 + l16;   // GEMM2 B rows (dout)
  const int nrow1 = (wave * 2 + 1) * 16 + l16;

  f32x4 acc_mo[NMT][2], acc_vo[NMT][2];
#pragma unroll
  for (int mt = 0; mt < NMT; ++mt)
#pragma unroll
    for (int j = 0; j < 2; ++j) {
      acc_mo[mt][j] = (f32x4){0.f, 0.f, 0.f, 0.f};
      acc_vo[mt][j] = (f32x4){0.f, 0.f, 0.f, 0.f};
    }

#pragma unroll 1
  for (int c = 0; c < 16; ++c) {   // 16 chunks x 64 RFs
    // ---- GEMM1: A = X frags (regs), B = W1 rows (R8's hoisted global) ----
    const ushort_t* w1m = W1mu  + (size_t)(c * 64 + wave * 16 + l16) * DIN + qoff;
    const uchar_t*  w1v = W1var8 + (size_t)(c * 64 + wave * 16 + l16) * DIN + qoff;
    bf16x8 bmu[8]; long long bvr[8];
#pragma unroll
    for (int k = 0; k < 8; ++k) {
      bmu[k] = *(const bf16x8*)(w1m + k * 32);
      bvr[k] = *(const long long*)(w1v + k * 32);
    }
    f32x4 am[NMT], av[NMT];
#pragma unroll
    for (int mt = 0; mt < NMT; ++mt) {
      am[mt] = (f32x4){0.f, 0.f, 0.f, 0.f};
      av[mt] = (f32x4){0.f, 0.f, 0.f, 0.f};
    }
#pragma unroll
    for (int k = 0; k < 8; ++k) {
#pragma unroll
      for (int mt = 0; mt < NMT; ++mt) {
        am[mt] = __builtin_amdgcn_mfma_f32_16x16x32_bf16(axr[mt][k], bmu[k], am[mt], 0, 0, 0);
        av[mt] = __builtin_amdgcn_mfma_f32_16x16x32_fp8_fp8(aqr[mt][k], bvr[k], av[mt], 0, 0, 0);
      }
    }

    // ---- preload GEMM2 B (global; latency overlaps moments) ----
    const ushort_t* w2m0 = W2mu + (size_t)nrow0 * NRF + c * 64 + qoff;
    const ushort_t* w2m1 = W2mu + (size_t)nrow1 * NRF + c * 64 + qoff;
    const uchar_t* w2b0 = W2b8 + (size_t)nrow0 * NRF + c * 64 + qoff;
    const uchar_t* w2b1 = W2b8 + (size_t)nrow1 * NRF + c * 64 + qoff;
    const uchar_t* w2v0 = W2var8 + (size_t)nrow0 * NRF + c * 64 + qoff;
    const uchar_t* w2v1 = W2var8 + (size_t)nrow1 * NRF + c * 64 + qoff;
    bf16x8 b2m[2][2]; long long b2b[2][2], b2v[2][2];
#pragma unroll
    for (int k2 = 0; k2 < 2; ++k2) {
      b2m[0][k2] = *(const bf16x8*)(w2m0 + k2 * 32);
      b2m[1][k2] = *(const bf16x8*)(w2m1 + k2 * 32);
      b2b[0][k2] = *(const long long*)(w2b0 + k2 * 32);
      b2b[1][k2] = *(const long long*)(w2b1 + k2 * 32);
      b2v[0][k2] = *(const long long*)(w2v0 + k2 * 32);
      b2v[1][k2] = *(const long long*)(w2v1 + k2 * 32);
    }

    // Barrier A: prior chunk's GEMM2 T-reads complete before overwrite.
    __syncthreads();

    // ---- ReLU moments via LUT -> Tm (bf16), Tv8 (fp8 v'), T38 (fp8 m'^2) ----
    const int col = wave * 16 + l16;   // chunk-local RF column
#pragma unroll
    for (int mt = 0; mt < NMT; ++mt) {
#pragma unroll
      for (int r = 0; r < 4; ++r) {
        float mu  = am[mt][r];
        float vpe = fmaf(av[mt][r], 0.00390625f, 1e-8f);  // descale + eps
        float rsq = fast_rsq(vpe);
        float z   = mu * rsq;
        float s   = vpe * rsq;
        float zc  = fminf(fmaxf(z, -8.0f), 7.96875f);
        float u   = fmaf(zc, 16.0f, 128.0f);              // [0, 255.5]
        float fu  = floorf(u);
        float f   = u - fu;
        float4 hv = htab[(int)fu];
        float h   = fmaf(f, hv.y, hv.x);
        float w   = fmaf(f, hv.w, hv.z);
        float mo  = (z > 7.9f) ? mu : s * h;              // exact linear tail
        float vo  = fmaxf(vpe * w, 1e-6f);
        int row = mt * 16 + quad * 4 + r;
        Tm[row * TMLD + col] = f2bf(mo);
        Tv8[row * TVLD + col] = (uchar_t)(cvt2_fp8<false>(vo, vo, 0u) & 0xffu);
        T38[row * TVLD + col] = (uchar_t)(cvt2_fp8<false>(mo * mo, mo * mo, 0u) & 0xffu);
      }
    }
    // Barrier B: T writes visible.
    __syncthreads();

    // ---- GEMM2 over this 64-RF chunk (2 K-steps) ----
#pragma unroll
    for (int k2 = 0; k2 < 2; ++k2) {
#pragma unroll
      for (int mt = 0; mt < NMT; ++mt) {
        int ar = mt * 16 + l16;
        bf16x8 fam = *(const bf16x8*)(Tm + ar * TMLD + k2 * 32 + qoff);
        long long fav = *(const long long*)(Tv8 + ar * TVLD + k2 * 32 + qoff);
        long long f3  = *(const long long*)(T38 + ar * TVLD + k2 * 32 + qoff);
        acc_mo[mt][0] = __builtin_amdgcn_mfma_f32_16x16x32_bf16(fam, b2m[0][k2], acc_mo[mt][0], 0, 0, 0);
        acc_mo[mt][1] = __builtin_amdgcn_mfma_f32_16x16x32_bf16(fam, b2m[1][k2], acc_mo[mt][1], 0, 0, 0);
        acc_vo[mt][0] = __builtin_amdgcn_mfma_f32_16x16x32_fp8_fp8(fav, b2b[0][k2], acc_vo[mt][0], 0, 0, 0);
        acc_vo[mt][1] = __builtin_amdgcn_mfma_f32_16x16x32_fp8_fp8(fav, b2b[1][k2], acc_vo[mt][1], 0, 0, 0);
        acc_vo[mt][0] = __builtin_amdgcn_mfma_f32_16x16x32_fp8_fp8(f3, b2v[0][k2], acc_vo[mt][0], 0, 0, 0);
        acc_vo[mt][1] = __builtin_amdgcn_mfma_f32_16x16x32_fp8_fp8(f3, b2v[1][k2], acc_vo[mt][1], 0, 0, 0);
      }
    }
  }

  // ---- epilogue: precision-weighted scatter (acc_vo carries x256 scale) ----
#pragma unroll
  for (int mt = 0; mt < NMT; ++mt)
#pragma unroll
    for (int j = 0; j < 2; ++j) {
      int dim = (wave * 2 + j) * 16 + l16;
#pragma unroll
      for (int r = 0; r < 4; ++r) {
        int prow = mt * 16 + quad * 4 + r;
        float mo = acc_mo[mt][j][r];
        float vo = fmaf(acc_vo[mt][j][r], 0.00390625f, 1e-6f);
        float prec = fast_rcp(vo);
        size_t o = (size_t)sidx[prow] * DOUT + dim;
        unsafeAtomicAdd(acc_means + o, prec * mo);
        unsafeAtomicAdd(acc_vars + o, prec);
      }
    }
}

// ---------------- kernel 3: finalize ------------------------------------------
__global__ __launch_bounds__(256) void finalize_kernel(float* __restrict__ means,
                                                       float* __restrict__ vars) {
  int i = blockIdx.x * 256 + threadIdx.x;   // covers S*DOUT exactly
  float p  = vars[i];
  float pm = means[i];
  float var = 1.0f / p;
  means[i] = pm * var;
  vars[i]  = var;
}

extern "C" void kernel_launch(void* const* d_in, const int* in_sizes, int n_in,
                              void* d_out, int out_size, void* d_ws, size_t ws_size,
                              hipStream_t stream) {
  const float*    X     = (const float*)d_in[0];
  const unsigned* Xidx  = (const unsigned*)d_in[1];
  const float*    W1mu  = (const float*)d_in[2];
  const float*    W1var = (const float*)d_in[3];
  const float*    W2mu  = (const float*)d_in[4];
  const float*    W2var = (const float*)d_in[5];
  float* out = (float*)d_out;

  ushort_t* w1mu_bf = (ushort_t*)d_ws;                    // 524288 B
  uchar_t*  w1var8  = (uchar_t*)(w1mu_bf + NRF * DIN);    // 262144 B
  ushort_t* w2mu_bf = (ushort_t*)(w1var8 + NRF * DIN);    // 262144 B
  uchar_t*  w2b8    = (uchar_t*)(w2mu_bf + NRF * DOUT);   // 131072 B
  uchar_t*  w2var8  = w2b8 + NRF * DOUT;                  // 131072 B
  float4*   htab    = (float4*)(w2var8 + NRF * DOUT);     // 4096 B (16-aligned)
  int* flag = (int*)(htab + 256);

  (void)hipMemsetAsync(d_out, 0, (size_t)out_size * sizeof(float), stream);
  detect_idx_kernel<<<1, 256, 0, stream>>>(Xidx, flag);
  moments_table_kernel<<<1, 256, 0, stream>>>(htab);
  convert_kernel<<<(NRF * DIN) / 4 / 256, 256, 0, stream>>>(
      W1mu, W1var, W2mu, W2var, w1mu_bf, w1var8, w2mu_bf, w2b8, w2var8);
  fused_kernel<<<NWG, 256, 0, stream>>>(
      X, Xidx, w1mu_bf, w1var8, w2mu_bf, w2b8, w2var8, htab, flag,
      out, out + (size_t)SGRP * DOUT);
  finalize_kernel<<<(SGRP * DOUT) / 256, 256, 0, stream>>>(
      out, out + (size_t)SGRP * DOUT);
}